// Round 3
// baseline (411.859 us; speedup 1.0000x reference)
//
#include <hip/hip_runtime.h>
#include <math.h>

// ---------------------------------------------------------------------------
// QuantumModel fused forward, v3: k-interleaved split-K=4, 4-deep x prefetch,
// double-buffered per-wave LDS weight broadcast. 256 thr/block, 64 rows/block.
// ---------------------------------------------------------------------------

__device__ float g_Ur[256];   // Re(U), row-major 16x16
__device__ float g_Ui[256];   // Im(U)
__device__ float g_Q[32];     // Q[j][t] = sum_i SIGNS[j][i]*post_w[i][t]

// --------------------------- setup kernel ----------------------------------
__global__ void build_unitary(const float* __restrict__ shared_w,
                              const float* __restrict__ task_w,
                              const float* __restrict__ post_w) {
  __shared__ float Ur[16][16];
  __shared__ float Ui[16][16];
  const int tid = threadIdx.x;        // 256 threads
  const int r = tid >> 4, c = tid & 15;
  Ur[r][c] = (r == c) ? 1.0f : 0.0f;
  Ui[r][c] = 0.0f;
  __syncthreads();

  for (int layer = 0; layer < 3; ++layer) {
    const float* w = (layer < 2) ? (shared_w + layer * 12) : task_w;
    const int lmod = (layer < 2) ? layer : 0;

    for (int q = 0; q < 4; ++q) {
      const float phi = w[q * 3 + 0], theta = w[q * 3 + 1], omega = w[q * 3 + 2];
      const float ch = cosf(theta * 0.5f), sh = sinf(theta * 0.5f);
      const float ap = -0.5f * (phi + omega);
      const float am = 0.5f * (phi - omega);
      const float cap = cosf(ap), sap = sinf(ap);
      const float cam = cosf(am), sam = sinf(am);
      const int mask = 1 << (3 - q);
      const int rp = r ^ mask;
      const bool hi = (r & mask) != 0;
      const float a_r = Ur[r][c],  a_i = Ui[r][c];
      const float b_r = Ur[rp][c], b_i = Ui[rp][c];
      __syncthreads();
      float nr, ni;
      if (!hi) {
        nr = ch * (cap * a_r - sap * a_i) - sh * (cam * b_r - sam * b_i);
        ni = ch * (cap * a_i + sap * a_r) - sh * (cam * b_i + sam * b_r);
      } else {
        nr = sh * (cam * b_r + sam * b_i) + ch * (cap * a_r + sap * a_i);
        ni = sh * (cam * b_i - sam * b_r) + ch * (cap * a_i - sap * a_r);
      }
      Ur[r][c] = nr; Ui[r][c] = ni;
      __syncthreads();
    }

    const int rr = lmod % 3 + 1;
    for (int q = 0; q < 4; ++q) {
      const int cbit = 1 << (3 - q);
      const int tbit = 1 << (3 - ((q + rr) & 3));
      const int src = (r & cbit) ? (r ^ tbit) : r;
      const float a_r = Ur[src][c], a_i = Ui[src][c];
      __syncthreads();
      Ur[r][c] = a_r; Ui[r][c] = a_i;
      __syncthreads();
    }
  }

  g_Ur[tid] = Ur[r][c];
  g_Ui[tid] = Ui[r][c];
  if (tid < 32) {
    const int j = tid >> 1, t = tid & 1;
    float acc = 0.0f;
    for (int i = 0; i < 4; ++i) {
      const float sgn = ((j >> (3 - i)) & 1) ? -1.0f : 1.0f;
      acc += sgn * post_w[i * 2 + t];
    }
    g_Q[tid] = acc;
  }
}

// --------------------------- main fused kernel -----------------------------
// 256 threads = 4 waves. Wave w == k-chunk c; all waves cover the same 64
// rows (rloc = lane). k interleaving: chunk c owns x float4-granules 4g+c,
// g = 0..48 (k = 16g+4c .. +3). Sibling waves consume each 64B line together.
#define RPB 64

__global__ __launch_bounds__(256, 5) void qm_fused(
    const float* __restrict__ x,
    const float* __restrict__ w1,   // (784,32) row-major
    const float* __restrict__ b1,
    const float* __restrict__ lg,
    const float* __restrict__ lb,
    const float* __restrict__ w2,   // (32,4) row-major
    const float* __restrict__ b2,
    const float* __restrict__ pb,   // post_b (2,)
    float* __restrict__ out,        // (B,2)
    int B) {
  __shared__ __align__(16) float stag[4][256];   // per-wave double-buffered w tile
  __shared__ float part[3 * RPB * 33];           // split-K partials, padded

  const int tid  = threadIdx.x;
  const int c    = tid >> 6;        // wave id == chunk 0..3
  const int lane = tid & 63;
  const int rglob = blockIdx.x * RPB + lane;

  const float4* __restrict__ xr4 =
      reinterpret_cast<const float4*>(x + (size_t)rglob * 784);
  // weights for granule g: 128 floats at w1 + 128*c + 512*g (rows 16g+4c..+3)
  const float* __restrict__ wbase = w1 + 128 * c + 2 * lane;
  float* __restrict__ st = &stag[c][0];

  float acc[32];
#pragma unroll
  for (int h = 0; h < 32; ++h) acc[h] = 0.0f;

  // ---- pipeline preload ----
  float2 wr0 = *reinterpret_cast<const float2*>(wbase);            // wgran 0
  float2 wr1 = *reinterpret_cast<const float2*>(wbase + 512);      // wgran 1
  *reinterpret_cast<float2*>(st + 2 * lane) = wr0;                 // slot0 <- g0
  wr0 = *reinterpret_cast<const float2*>(wbase + 1024);            // wgran 2
  float4 xq0 = xr4[c];
  float4 xq1 = xr4[4 + c];
  float4 xq2 = xr4[8 + c];
  float4 xq3 = xr4[12 + c];

#define COMPUTE_GRANULE(XC, SLOT)                                          \
  {                                                                        \
    const float xs[4] = {(XC).x, (XC).y, (XC).z, (XC).w};                  \
    _Pragma("unroll") for (int kk = 0; kk < 4; ++kk) {                     \
      const float xv = xs[kk];                                             \
      _Pragma("unroll") for (int h4 = 0; h4 < 8; ++h4) {                   \
        const float4 wv = *reinterpret_cast<const float4*>(                \
            st + (SLOT)*128 + kk * 32 + h4 * 4);                           \
        acc[h4 * 4 + 0] = fmaf(wv.x, xv, acc[h4 * 4 + 0]);                 \
        acc[h4 * 4 + 1] = fmaf(wv.y, xv, acc[h4 * 4 + 1]);                 \
        acc[h4 * 4 + 2] = fmaf(wv.z, xv, acc[h4 * 4 + 2]);                 \
        acc[h4 * 4 + 3] = fmaf(wv.w, xv, acc[h4 * 4 + 3]);                 \
      }                                                                    \
    }                                                                      \
  }

  // granules 0..47, 4 per macro-iteration; all ring indices static.
#pragma unroll 1
  for (int mb = 0; mb < 12; ++mb) {
    const int g = mb * 4;
    int gw, gx;
    // ---- u = 0 (g even): write slot1 <- wr1 (wgran g+1), reload wr1 ----
    *reinterpret_cast<float2*>(st + 128 + 2 * lane) = wr1;
    gw = g + 3; if (gw > 48) gw = 48;
    wr1 = *reinterpret_cast<const float2*>(wbase + 512 * gw);
    {
      const float4 xc = xq0;
      gx = g + 4; if (gx > 48) gx = 48;
      xq0 = xr4[4 * gx + c];
      COMPUTE_GRANULE(xc, 0)
    }
    // ---- u = 1: write slot0 <- wr0 (wgran g+2), reload wr0 ----
    *reinterpret_cast<float2*>(st + 2 * lane) = wr0;
    gw = g + 4; if (gw > 48) gw = 48;
    wr0 = *reinterpret_cast<const float2*>(wbase + 512 * gw);
    {
      const float4 xc = xq1;
      gx = g + 5; if (gx > 48) gx = 48;
      xq1 = xr4[4 * gx + c];
      COMPUTE_GRANULE(xc, 1)
    }
    // ---- u = 2: write slot1 <- wr1 (wgran g+3), reload wr1 ----
    *reinterpret_cast<float2*>(st + 128 + 2 * lane) = wr1;
    gw = g + 5; if (gw > 48) gw = 48;
    wr1 = *reinterpret_cast<const float2*>(wbase + 512 * gw);
    {
      const float4 xc = xq2;
      gx = g + 6; if (gx > 48) gx = 48;
      xq2 = xr4[4 * gx + c];
      COMPUTE_GRANULE(xc, 0)
    }
    // ---- u = 3: write slot0 <- wr0 (wgran g+4), reload wr0 ----
    *reinterpret_cast<float2*>(st + 2 * lane) = wr0;
    gw = g + 6; if (gw > 48) gw = 48;
    wr0 = *reinterpret_cast<const float2*>(wbase + 512 * gw);
    {
      const float4 xc = xq3;
      gx = g + 7; if (gx > 48) gx = 48;
      xq3 = xr4[4 * gx + c];
      COMPUTE_GRANULE(xc, 1)
    }
  }
  // ---- tail granule 48: slot0 was written with wgran 48 at g=47 ----
  COMPUTE_GRANULE(xq0, 0)

  // --- split-K reduction: chunks 1..3 park partials in LDS ---
  if (c > 0) {
    float* p = &part[((c - 1) * RPB + lane) * 33];
#pragma unroll
    for (int h = 0; h < 32; ++h) p[h] = acc[h];
  }
  __syncthreads();

  if (tid < RPB) {   // wave 0 == chunk 0, row = tid
#pragma unroll
    for (int cc = 0; cc < 3; ++cc) {
      const float* p = &part[(cc * RPB + tid) * 33];
#pragma unroll
      for (int h = 0; h < 32; ++h) acc[h] += p[h];
    }

    // --- bias + relu + layernorm ---
    float mu = 0.0f, sq = 0.0f;
#pragma unroll
    for (int h = 0; h < 32; ++h) {
      float v = fmaxf(acc[h] + b1[h], 0.0f);
      acc[h] = v;
      mu += v;
      sq += v * v;
    }
    mu *= (1.0f / 32.0f);
    sq *= (1.0f / 32.0f);
    const float inv = rsqrtf(sq - mu * mu + 1e-5f);

    // --- z = tanh(hn @ W2 + b2) -> angles -> single-qubit states ---
    float z[4] = {b2[0], b2[1], b2[2], b2[3]};
#pragma unroll
    for (int h = 0; h < 32; ++h) {
      const float hn = (acc[h] - mu) * inv * lg[h] + lb[h];
#pragma unroll
      for (int j = 0; j < 4; ++j) z[j] = fmaf(hn, w2[h * 4 + j], z[j]);
    }
    float cq[4], sn[4];
#pragma unroll
    for (int j = 0; j < 4; ++j) {
      const float half = tanhf(z[j]) * 1.5707963267948966f;
      __sincosf(half, &sn[j], &cq[j]);
    }

    // --- psi: 4-fold kron, qubit 0 = MSB ---
    float psi[16];
#pragma unroll
    for (int b = 0; b < 16; ++b) {
      float p = ((b >> 3) & 1) ? sn[0] : cq[0];
      p *= ((b >> 2) & 1) ? sn[1] : cq[1];
      p *= ((b >> 1) & 1) ? sn[2] : cq[2];
      p *= (b & 1) ? sn[3] : cq[3];
      psi[b] = p;
    }

    // --- out_t = pb_t + sum_j Q[j][t] * |U_j . psi|^2 ---
    float o0 = pb[0], o1 = pb[1];
#pragma unroll
    for (int j = 0; j < 16; ++j) {
      float re = 0.0f, im = 0.0f;
#pragma unroll
      for (int k = 0; k < 16; ++k) {
        re = fmaf(g_Ur[j * 16 + k], psi[k], re);
        im = fmaf(g_Ui[j * 16 + k], psi[k], im);
      }
      const float p = re * re + im * im;
      o0 = fmaf(g_Q[j * 2 + 0], p, o0);
      o1 = fmaf(g_Q[j * 2 + 1], p, o1);
    }
    const int rg = blockIdx.x * RPB + tid;
    reinterpret_cast<float2*>(out)[rg] = make_float2(o0, o1);
  }
}

// --------------------------- launcher --------------------------------------
extern "C" void kernel_launch(void* const* d_in, const int* in_sizes, int n_in,
                              void* d_out, int out_size, void* d_ws, size_t ws_size,
                              hipStream_t stream) {
  const float* x  = (const float*)d_in[0];
  const float* w1 = (const float*)d_in[1];
  const float* b1 = (const float*)d_in[2];
  const float* lg = (const float*)d_in[3];
  const float* lb = (const float*)d_in[4];
  const float* w2 = (const float*)d_in[5];
  const float* b2 = (const float*)d_in[6];
  const float* sw = (const float*)d_in[7];
  const float* tw = (const float*)d_in[8];
  const float* pw = (const float*)d_in[9];
  const float* pb = (const float*)d_in[10];
  float* out = (float*)d_out;

  const int B = in_sizes[0] / 784;   // 65536, divisible by 64

  hipLaunchKernelGGL(build_unitary, dim3(1), dim3(256), 0, stream, sw, tw, pw);
  hipLaunchKernelGGL(qm_fused, dim3(B / RPB), dim3(256), 0, stream,
                     x, w1, b1, lg, lb, w2, b2, pb, out, B);
}

// Round 4
// 338.565 us; speedup vs baseline: 1.2165x; 1.2165x over previous
//
#include <hip/hip_runtime.h>
#include <math.h>

// ---------------------------------------------------------------------------
// QuantumModel fused forward, v4: encoder GEMM on MFMA f16 (16x16x16),
// weights pre-packed into per-lane fragment order, tail in fp32 VALU.
// ---------------------------------------------------------------------------

typedef _Float16 half4_t __attribute__((ext_vector_type(4)));
typedef float f32x4 __attribute__((ext_vector_type(4)));

__device__ float g_Ur[256];                 // Re(U), row-major 16x16
__device__ float g_Ui[256];                 // Im(U)
__device__ float g_Q[32];                   // SIGNS @ post_w, (16,2)
__device__ __align__(16) _Float16 g_B[49 * 2 * 64 * 4];  // [s][t][lane][j]

// --------------------------- prep kernel -----------------------------------
// Builds U (16x16 complex), Q, and the fp16-packed W1 fragment stream.
__global__ void prep(const float* __restrict__ shared_w,
                     const float* __restrict__ task_w,
                     const float* __restrict__ post_w,
                     const float* __restrict__ w1) {
  __shared__ float Ur[16][16];
  __shared__ float Ui[16][16];
  const int tid = threadIdx.x;        // 256 threads
  const int r = tid >> 4, c = tid & 15;
  Ur[r][c] = (r == c) ? 1.0f : 0.0f;
  Ui[r][c] = 0.0f;
  __syncthreads();

  for (int layer = 0; layer < 3; ++layer) {
    const float* w = (layer < 2) ? (shared_w + layer * 12) : task_w;
    const int lmod = (layer < 2) ? layer : 0;

    for (int q = 0; q < 4; ++q) {
      const float phi = w[q * 3 + 0], theta = w[q * 3 + 1], omega = w[q * 3 + 2];
      const float ch = cosf(theta * 0.5f), sh = sinf(theta * 0.5f);
      const float ap = -0.5f * (phi + omega);
      const float am = 0.5f * (phi - omega);
      const float cap = cosf(ap), sap = sinf(ap);
      const float cam = cosf(am), sam = sinf(am);
      const int mask = 1 << (3 - q);
      const int rp = r ^ mask;
      const bool hi = (r & mask) != 0;
      const float a_r = Ur[r][c],  a_i = Ui[r][c];
      const float b_r = Ur[rp][c], b_i = Ui[rp][c];
      __syncthreads();
      float nr, ni;
      if (!hi) {
        nr = ch * (cap * a_r - sap * a_i) - sh * (cam * b_r - sam * b_i);
        ni = ch * (cap * a_i + sap * a_r) - sh * (cam * b_i + sam * b_r);
      } else {
        nr = sh * (cam * b_r + sam * b_i) + ch * (cap * a_r + sap * a_i);
        ni = sh * (cam * b_i - sam * b_r) + ch * (cap * a_i - sap * a_r);
      }
      Ur[r][c] = nr; Ui[r][c] = ni;
      __syncthreads();
    }

    const int rr = lmod % 3 + 1;
    for (int q = 0; q < 4; ++q) {
      const int cbit = 1 << (3 - q);
      const int tbit = 1 << (3 - ((q + rr) & 3));
      const int src = (r & cbit) ? (r ^ tbit) : r;
      const float a_r = Ur[src][c], a_i = Ui[src][c];
      __syncthreads();
      Ur[r][c] = a_r; Ui[r][c] = a_i;
      __syncthreads();
    }
  }

  g_Ur[tid] = Ur[r][c];
  g_Ui[tid] = Ui[r][c];
  if (tid < 32) {
    const int j = tid >> 1, t = tid & 1;
    float acc = 0.0f;
    for (int i = 0; i < 4; ++i) {
      const float sgn = ((j >> (3 - i)) & 1) ? -1.0f : 1.0f;
      acc += sgn * post_w[i * 2 + t];
    }
    g_Q[tid] = acc;
  }

  // pack W1 (784x32 fp32) -> fp16 B-fragments: idx = ((s*2+t)*64+l)*4+j,
  // value = w1[(16s + (l>>4)*4 + j)*32 + 16t + (l&15)]
  for (int idx = tid; idx < 49 * 512; idx += 256) {
    const int j = idx & 3;
    const int l = (idx >> 2) & 63;
    const int t = (idx >> 8) & 1;
    const int s = idx >> 9;
    const int k = 16 * s + ((l >> 4) << 2) + j;
    const int n = 16 * t + (l & 15);
    g_B[idx] = (_Float16)w1[k * 32 + n];
  }
}

// --------------------------- main fused kernel -----------------------------
// 256 threads = 4 waves; wave w computes a 16-row M-tile via MFMA f16,
// parks C (16x32 fp32) in LDS; threads 0-63 then run one row-tail each.
__global__ __launch_bounds__(256) void qm_fused(
    const float* __restrict__ x,
    const float* __restrict__ b1,
    const float* __restrict__ lg,
    const float* __restrict__ lb,
    const float* __restrict__ w2,   // (32,4) row-major
    const float* __restrict__ b2,
    const float* __restrict__ pb,   // post_b (2,)
    float* __restrict__ out,        // (B,2)
    int B) {
  __shared__ float cpark[4][16][33];   // per-wave C tiles, padded

  const int tid = threadIdx.x;
  const int w   = tid >> 6;
  const int l   = tid & 63;
  const int m   = l & 15;            // A-fragment row
  const int kq  = l >> 4;            // k-quad 0..3
  const int row = blockIdx.x * 64 + w * 16 + m;

  const float* __restrict__ xa = x + (size_t)row * 784 + kq * 4;
  const _Float16* __restrict__ bb = g_B + l * 4;

  f32x4 acc0 = {0.f, 0.f, 0.f, 0.f};
  f32x4 acc1 = {0.f, 0.f, 0.f, 0.f};

  // register rings: A 4 deep (HBM), B 2 deep (L1/L2)
  float4 ar0 = *reinterpret_cast<const float4*>(xa + 0 * 16);
  float4 ar1 = *reinterpret_cast<const float4*>(xa + 1 * 16);
  float4 ar2 = *reinterpret_cast<const float4*>(xa + 2 * 16);
  float4 ar3 = *reinterpret_cast<const float4*>(xa + 3 * 16);
  half4_t b0s0 = *reinterpret_cast<const half4_t*>(bb + 0 * 512);
  half4_t b1s0 = *reinterpret_cast<const half4_t*>(bb + 0 * 512 + 256);
  half4_t b0s1 = *reinterpret_cast<const half4_t*>(bb + 1 * 512);
  half4_t b1s1 = *reinterpret_cast<const half4_t*>(bb + 1 * 512 + 256);

#define QSTEP(S_, AR, B0, B1)                                                 \
  {                                                                           \
    const float4 av = AR;                                                     \
    constexpr int pfa = ((S_) + 4 > 48) ? 48 : (S_) + 4;                      \
    AR = *reinterpret_cast<const float4*>(xa + pfa * 16);                     \
    constexpr int pfb = ((S_) + 2 > 48) ? 48 : (S_) + 2;                      \
    const half4_t bu0 = B0, bu1 = B1;                                         \
    B0 = *reinterpret_cast<const half4_t*>(bb + pfb * 512);                   \
    B1 = *reinterpret_cast<const half4_t*>(bb + pfb * 512 + 256);             \
    const half4_t af = {(_Float16)av.x, (_Float16)av.y, (_Float16)av.z,       \
                        (_Float16)av.w};                                      \
    acc0 = __builtin_amdgcn_mfma_f32_16x16x16f16(af, bu0, acc0, 0, 0, 0);     \
    acc1 = __builtin_amdgcn_mfma_f32_16x16x16f16(af, bu1, acc1, 0, 0, 0);     \
  }

#pragma unroll 1
  for (int mb = 0; mb < 12; ++mb) {
    switch (mb) {   // S_ must be a compile-time constant for imm offsets
#define MB_CASE(MB_)                                                          \
      case MB_:                                                               \
        QSTEP(4 * MB_ + 0, ar0, b0s0, b1s0)                                   \
        QSTEP(4 * MB_ + 1, ar1, b0s1, b1s1)                                   \
        QSTEP(4 * MB_ + 2, ar2, b0s0, b1s0)                                   \
        QSTEP(4 * MB_ + 3, ar3, b0s1, b1s1)                                   \
        break;
      MB_CASE(0) MB_CASE(1) MB_CASE(2) MB_CASE(3) MB_CASE(4) MB_CASE(5)
      MB_CASE(6) MB_CASE(7) MB_CASE(8) MB_CASE(9) MB_CASE(10) MB_CASE(11)
#undef MB_CASE
    }
  }
  QSTEP(48, ar0, b0s0, b1s0)   // final step; prefetches clamp to 48

  // park C tile: lane holds rows kq*4+r, cols m (acc0) and m+16 (acc1)
#pragma unroll
  for (int r = 0; r < 4; ++r) {
    cpark[w][kq * 4 + r][m]      = acc0[r];
    cpark[w][kq * 4 + r][m + 16] = acc1[r];
  }
  __syncthreads();

  // ------------------------------ tail -------------------------------------
  if (tid < 64) {
    float acc[32];
#pragma unroll
    for (int h = 0; h < 32; ++h) acc[h] = cpark[tid >> 4][tid & 15][h];

    float mu = 0.0f, sq = 0.0f;
#pragma unroll
    for (int h = 0; h < 32; ++h) {
      float v = fmaxf(acc[h] + b1[h], 0.0f);
      acc[h] = v;
      mu += v;
      sq += v * v;
    }
    mu *= (1.0f / 32.0f);
    sq *= (1.0f / 32.0f);
    const float inv = rsqrtf(sq - mu * mu + 1e-5f);

    float z[4] = {b2[0], b2[1], b2[2], b2[3]};
#pragma unroll
    for (int h = 0; h < 32; ++h) {
      const float hn = (acc[h] - mu) * inv * lg[h] + lb[h];
#pragma unroll
      for (int j = 0; j < 4; ++j) z[j] = fmaf(hn, w2[h * 4 + j], z[j]);
    }
    float cq[4], sn[4];
#pragma unroll
    for (int j = 0; j < 4; ++j) {
      const float half = tanhf(z[j]) * 1.5707963267948966f;
      __sincosf(half, &sn[j], &cq[j]);
    }

    float psi[16];
#pragma unroll
    for (int b = 0; b < 16; ++b) {
      float p = ((b >> 3) & 1) ? sn[0] : cq[0];
      p *= ((b >> 2) & 1) ? sn[1] : cq[1];
      p *= ((b >> 1) & 1) ? sn[2] : cq[2];
      p *= (b & 1) ? sn[3] : cq[3];
      psi[b] = p;
    }

    float o0 = pb[0], o1 = pb[1];
#pragma unroll
    for (int j = 0; j < 16; ++j) {
      float re = 0.0f, im = 0.0f;
#pragma unroll
      for (int k = 0; k < 16; ++k) {
        re = fmaf(g_Ur[j * 16 + k], psi[k], re);
        im = fmaf(g_Ui[j * 16 + k], psi[k], im);
      }
      const float p = re * re + im * im;
      o0 = fmaf(g_Q[j * 2 + 0], p, o0);
      o1 = fmaf(g_Q[j * 2 + 1], p, o1);
    }
    const int rg = blockIdx.x * 64 + tid;
    reinterpret_cast<float2*>(out)[rg] = make_float2(o0, o1);
  }
}

// --------------------------- launcher --------------------------------------
extern "C" void kernel_launch(void* const* d_in, const int* in_sizes, int n_in,
                              void* d_out, int out_size, void* d_ws, size_t ws_size,
                              hipStream_t stream) {
  const float* x  = (const float*)d_in[0];
  const float* w1 = (const float*)d_in[1];
  const float* b1 = (const float*)d_in[2];
  const float* lg = (const float*)d_in[3];
  const float* lb = (const float*)d_in[4];
  const float* w2 = (const float*)d_in[5];
  const float* b2 = (const float*)d_in[6];
  const float* sw = (const float*)d_in[7];
  const float* tw = (const float*)d_in[8];
  const float* pw = (const float*)d_in[9];
  const float* pb = (const float*)d_in[10];
  float* out = (float*)d_out;

  const int B = in_sizes[0] / 784;   // 65536, divisible by 64

  hipLaunchKernelGGL(prep, dim3(1), dim3(256), 0, stream, sw, tw, pw, w1);
  hipLaunchKernelGGL(qm_fused, dim3(B / 64), dim3(256), 0, stream,
                     x, b1, lg, lb, w2, b2, pb, out, B);
}